// Round 1
// baseline (1095.932 us; speedup 1.0000x reference)
//
#include <hip/hip_runtime.h>
#include <hip/hip_bf16.h>
#include <cstdint>

#define B_   2
#define S_   2048
#define HID_ 3072
#define H_   16
#define KV_  8
#define D_   256
#define HD_  4096   // H_*D_
#define KVD_ 2048   // KV_*D_

constexpr float EPS_   = 1e-6f;
constexpr float SCALE_ = 0.0625f;   // 256^-0.5

typedef unsigned short u16;
typedef __attribute__((ext_vector_type(8))) short bf16x8;
typedef __attribute__((ext_vector_type(4))) float f32x4;

__device__ inline float bf2f(u16 u) { return __uint_as_float(((unsigned int)u) << 16); }
__device__ inline u16 f2bf(float f) {
  unsigned int x = __float_as_uint(f);
  x += 0x7fffu + ((x >> 16) & 1u);   // RNE
  return (u16)(x >> 16);
}

// ---------------- elementwise cast f32 -> bf16 (n4 = n/4) ----------------
__global__ void cast_f32_bf16(const float* __restrict__ in, u16* __restrict__ out, int n4) {
  int i = blockIdx.x * blockDim.x + threadIdx.x;
  if (i < n4) {
    float4 v = ((const float4*)in)[i];
    ushort4 o;
    o.x = f2bf(v.x); o.y = f2bf(v.y); o.z = f2bf(v.z); o.w = f2bf(v.w);
    ((ushort4*)out)[i] = o;
  }
}

// ------------- transpose+cast: in[K][N] f32 -> out[N][K] bf16 -------------
__global__ void transpose_cast(const float* __restrict__ in, u16* __restrict__ out, int K, int N) {
  __shared__ __align__(16) float tile[64][65];
  int n0 = blockIdx.x * 64, k0 = blockIdx.y * 64;
  int t = threadIdx.x;
  int rr = t >> 4, cc = (t & 15) * 4;
  for (int i = 0; i < 4; i++) {
    float4 v = *(const float4*)(&in[(size_t)(k0 + rr + 16 * i) * N + n0 + cc]);
    tile[rr + 16 * i][cc + 0] = v.x; tile[rr + 16 * i][cc + 1] = v.y;
    tile[rr + 16 * i][cc + 2] = v.z; tile[rr + 16 * i][cc + 3] = v.w;
  }
  __syncthreads();
  for (int i = 0; i < 4; i++) {
    int orow = rr + 16 * i;  // n index
    ushort4 o;
    o.x = f2bf(tile[cc + 0][orow]); o.y = f2bf(tile[cc + 1][orow]);
    o.z = f2bf(tile[cc + 2][orow]); o.w = f2bf(tile[cc + 3][orow]);
    *(ushort4*)(&out[(size_t)(n0 + orow) * K + k0 + cc]) = o;
  }
}

// --------- GEMM: C[M][N] = A[M][K] * Bt[N][K]^T, bf16 in, f32 acc ---------
// 128x128 tile, BK=32, 256 threads (4 waves 2x2, each wave 64x64 = 4x4 mfma tiles)
template <bool OUTF32>
__global__ __launch_bounds__(256) void gemm_bf16(const u16* __restrict__ A,
                                                 const u16* __restrict__ Bt,
                                                 void* __restrict__ Cv, int M, int N, int K) {
  __shared__ __align__(16) u16 As[128 * 40];
  __shared__ __align__(16) u16 Bs[128 * 40];
  int t = threadIdx.x, lane = t & 63, wave = t >> 6;
  int wm = wave >> 1, wn = wave & 1, quad = lane >> 4, l16 = lane & 15;
  int bm = blockIdx.y * 128, bn = blockIdx.x * 128;
  f32x4 acc[4][4] = {};
  int arow0 = t >> 2, ac8 = (t & 3) * 8;
  for (int k0 = 0; k0 < K; k0 += 32) {
    __syncthreads();
    for (int s = 0; s < 2; s++) {
      int row = arow0 + s * 64;
      uint4 av = *(const uint4*)(&A[(size_t)(bm + row) * K + k0 + ac8]);
      *(uint4*)(&As[row * 40 + ac8]) = av;
      uint4 bv = *(const uint4*)(&Bt[(size_t)(bn + row) * K + k0 + ac8]);
      *(uint4*)(&Bs[row * 40 + ac8]) = bv;
    }
    __syncthreads();
    bf16x8 af[4], bfr[4];
    for (int i = 0; i < 4; i++)
      af[i] = *(const bf16x8*)(&As[(wm * 64 + i * 16 + l16) * 40 + quad * 8]);
    for (int j = 0; j < 4; j++)
      bfr[j] = *(const bf16x8*)(&Bs[(wn * 64 + j * 16 + l16) * 40 + quad * 8]);
    for (int i = 0; i < 4; i++)
      for (int j = 0; j < 4; j++)
        acc[i][j] = __builtin_amdgcn_mfma_f32_16x16x32_bf16(af[i], bfr[j], acc[i][j], 0, 0, 0);
  }
  for (int i = 0; i < 4; i++)
    for (int j = 0; j < 4; j++)
      for (int r = 0; r < 4; r++) {
        int row = bm + wm * 64 + i * 16 + quad * 4 + r;
        int col = bn + wn * 64 + j * 16 + l16;
        float v = acc[i][j][r];
        if (OUTF32) ((float*)Cv)[(size_t)row * N + col] = v;
        else ((u16*)Cv)[(size_t)row * N + col] = f2bf(v);
      }
}

// ----- fused RMSNorm + RoPE, in place on bf16 [B*S][nh][256]; 1 wave/head -----
__global__ void rmsnorm_rope(u16* __restrict__ x, const float* __restrict__ w,
                             const float* __restrict__ fc, const float* __restrict__ fsn,
                             int nh, float outscale) {
  int token = blockIdx.x;
  int head = blockIdx.y * 4 + (threadIdx.x >> 6);
  if (head >= nh) return;
  int lane = threadIdx.x & 63;
  int s = token & (S_ - 1);
  u16* p = x + (size_t)(token * nh + head) * D_;
  float v0 = bf2f(p[lane]);
  float v1 = bf2f(p[lane + 64]);
  float v2 = bf2f(p[lane + 128]);
  float v3 = bf2f(p[lane + 192]);
  float ss = v0 * v0 + v1 * v1 + v2 * v2 + v3 * v3;
  for (int off = 32; off; off >>= 1) ss += __shfl_xor(ss, off, 64);
  float rs = rsqrtf(ss * (1.0f / D_) + EPS_);
  float n0 = v0 * rs * (1.0f + w[lane]);
  float n1 = v1 * rs * (1.0f + w[lane + 64]);
  float n2 = v2 * rs * (1.0f + w[lane + 128]);
  float n3 = v3 * rs * (1.0f + w[lane + 192]);
  float c0 = fc[s * 128 + lane], s0 = fsn[s * 128 + lane];
  float c1 = fc[s * 128 + lane + 64], s1 = fsn[s * 128 + lane + 64];
  p[lane]       = f2bf((n0 * c0 - n2 * s0) * outscale);
  p[lane + 128] = f2bf((n0 * s0 + n2 * c0) * outscale);
  p[lane + 64]  = f2bf((n1 * c1 - n3 * s1) * outscale);
  p[lane + 192] = f2bf((n1 * s1 + n3 * c1) * outscale);
}

// ---------------- flash attention, causal, GQA rep=2, D=256 ----------------
// grid (S/64, H, B), 256 threads; wave handles 16 q rows; 32-key tiles in LDS
__global__ __launch_bounds__(256) void flash_attn(const u16* __restrict__ Q,
                                                  const u16* __restrict__ Kb,
                                                  const u16* __restrict__ Vb,
                                                  u16* __restrict__ O) {
  __shared__ __align__(16) u16 Ks[32 * 264];     // K rows, padded (+8 bf16)
  __shared__ __align__(16) u16 Vs[256 * 40];     // V transposed: Vt[d][key], padded
  __shared__ __align__(16) u16 Ps[4][16 * 32];   // per-wave P round-trip
  int t = threadIdx.x, lane = t & 63, wave = t >> 6;
  int quad = lane >> 4, l16 = lane & 15;
  int qb = blockIdx.x * 64;
  int h = blockIdx.y, b = blockIdx.z;
  int kvh = h >> 1;
  int qw = qb + wave * 16;

  // Q fragments (A-layout) straight from global
  bf16x8 qf[8];
  const u16* qp = Q + ((size_t)(b * S_) + qw + l16) * HD_ + h * D_;
  for (int c = 0; c < 8; c++) qf[c] = *(const bf16x8*)(qp + c * 32 + quad * 8);

  f32x4 o_acc[16] = {};
  float m_r[4], l_r[4];
  for (int r = 0; r < 4; r++) { m_r[r] = -3e38f; l_r[r] = 0.f; }

  int nkt = (qb + 64) >> 5;
  const u16* kbase = Kb + (size_t)b * S_ * KVD_ + kvh * D_;
  const u16* vbase = Vb + (size_t)b * S_ * KVD_ + kvh * D_;

  for (int kt = 0; kt < nkt; kt++) {
    __syncthreads();
    {  // stage K rows [32][256] -> Ks (row stride 264)
      int key = t >> 5, cw = (t & 31) * 8;
      for (int p = 0; p < 4; p++) {
        int kk = key + p * 8;
        uint4 v = *(const uint4*)(kbase + (size_t)(kt * 32 + kk) * KVD_ + cw);
        *(uint4*)(&Ks[kk * 264 + cw]) = v;
      }
    }
    {  // stage V transposed: lane owns d=t, packs 32 keys -> 4x b128 writes
      u16 hold[32];
      const u16* vp = vbase + (size_t)(kt * 32) * KVD_ + t;
#pragma unroll
      for (int kk = 0; kk < 32; kk++) hold[kk] = vp[(size_t)kk * KVD_];
#pragma unroll
      for (int g = 0; g < 4; g++) {
        uint4 wv;
        wv.x = (unsigned)hold[g * 8 + 0] | ((unsigned)hold[g * 8 + 1] << 16);
        wv.y = (unsigned)hold[g * 8 + 2] | ((unsigned)hold[g * 8 + 3] << 16);
        wv.z = (unsigned)hold[g * 8 + 4] | ((unsigned)hold[g * 8 + 5] << 16);
        wv.w = (unsigned)hold[g * 8 + 6] | ((unsigned)hold[g * 8 + 7] << 16);
        *(uint4*)(&Vs[t * 40 + g * 8]) = wv;
      }
    }
    __syncthreads();

    // scores S[16q x 32k] as two 16x16 C-tiles
    f32x4 sc0 = {}, sc1 = {};
    for (int c = 0; c < 8; c++) {
      bf16x8 k0 = *(const bf16x8*)(&Ks[l16 * 264 + c * 32 + quad * 8]);
      bf16x8 k1 = *(const bf16x8*)(&Ks[(l16 + 16) * 264 + c * 32 + quad * 8]);
      sc0 = __builtin_amdgcn_mfma_f32_16x16x32_bf16(qf[c], k0, sc0, 0, 0, 0);
      sc1 = __builtin_amdgcn_mfma_f32_16x16x32_bf16(qf[c], k1, sc1, 0, 0, 0);
    }
    // online softmax (scale already folded into Q)
    int kg0 = kt * 32 + l16, kg1 = kg0 + 16;
    float p0[4], p1[4], alpha[4];
    for (int r = 0; r < 4; r++) {
      int qg = qw + quad * 4 + r;
      float a = (kg0 <= qg) ? sc0[r] : -1e30f;
      float bb = (kg1 <= qg) ? sc1[r] : -1e30f;
      float mx = fmaxf(a, bb);
      for (int off = 1; off < 16; off <<= 1) mx = fmaxf(mx, __shfl_xor(mx, off, 16));
      float mnew = fmaxf(m_r[r], mx);
      alpha[r] = __expf(m_r[r] - mnew);
      m_r[r] = mnew;
      float e0 = __expf(a - mnew);
      float e1 = __expf(bb - mnew);
      p0[r] = e0; p1[r] = e1;
      float rsum = e0 + e1;
      for (int off = 1; off < 16; off <<= 1) rsum += __shfl_xor(rsum, off, 16);
      l_r[r] = l_r[r] * alpha[r] + rsum;
    }
    for (int nt = 0; nt < 16; nt++)
      for (int r = 0; r < 4; r++) o_acc[nt][r] *= alpha[r];
    // P: C-layout -> LDS -> A-layout
    u16* pw = &Ps[wave][0];
    for (int r = 0; r < 4; r++) {
      pw[(quad * 4 + r) * 32 + l16] = f2bf(p0[r]);
      pw[(quad * 4 + r) * 32 + l16 + 16] = f2bf(p1[r]);
    }
    asm volatile("s_waitcnt lgkmcnt(0)" ::: "memory");
    bf16x8 pf = *(const bf16x8*)(&pw[l16 * 32 + quad * 8]);
    for (int nt = 0; nt < 16; nt++) {
      bf16x8 vf = *(const bf16x8*)(&Vs[(nt * 16 + l16) * 40 + quad * 8]);
      o_acc[nt] = __builtin_amdgcn_mfma_f32_16x16x32_bf16(pf, vf, o_acc[nt], 0, 0, 0);
    }
  }
  // epilogue: O / l
  for (int r = 0; r < 4; r++) {
    int qg = qw + quad * 4 + r;
    float inv = 1.0f / l_r[r];
    u16* op = O + ((size_t)(b * S_) + qg) * HD_ + h * D_;
    for (int nt = 0; nt < 16; nt++) op[nt * 16 + l16] = f2bf(o_acc[nt][r] * inv);
  }
}

extern "C" void kernel_launch(void* const* d_in, const int* in_sizes, int n_in,
                              void* d_out, int out_size, void* d_ws, size_t ws_size,
                              hipStream_t stream) {
  const float* hs  = (const float*)d_in[0];
  const float* fc  = (const float*)d_in[1];
  const float* fsn = (const float*)d_in[2];
  // d_in[3] = mask: causal, replicated analytically
  const float* qw  = (const float*)d_in[4];
  const float* kw  = (const float*)d_in[5];
  const float* vw  = (const float*)d_in[6];
  const float* ow  = (const float*)d_in[7];
  const float* qnw = (const float*)d_in[8];
  const float* knw = (const float*)d_in[9];

  char* ws = (char*)d_ws;
  // layout (bytes):
  u16* x_bf = (u16*)(ws + 0);           // 4096*3072*2  = 25165824
  u16* qw_t = (u16*)(ws + 25165824);    // 4096*3072*2  = 25165824
  u16* kw_t = (u16*)(ws + 50331648);    // 2048*3072*2  = 12582912
  u16* vw_t = (u16*)(ws + 62914560);    // 2048*3072*2  = 12582912
  u16* ow_t = (u16*)(ws + 75497472);    // 3072*4096*2  = 25165824
  u16* xq   = (u16*)(ws + 100663296);   // 4096*4096*2  = 33554432
  u16* xk   = (u16*)(ws + 134217728);   // 4096*2048*2  = 16777216
  u16* xv   = (u16*)(ws + 150994944);   // 4096*2048*2  = 16777216  -> end 167772160
  u16* attn = (u16*)(ws + 25165824);    // overlays dead qw_t/kw_t region (33.5MB <= 37.7MB)

  cast_f32_bf16<<<12288, 256, 0, stream>>>(hs, x_bf, 4096 * 3072 / 4);
  transpose_cast<<<dim3(64, 48), 256, 0, stream>>>(qw, qw_t, 3072, 4096);
  transpose_cast<<<dim3(32, 48), 256, 0, stream>>>(kw, kw_t, 3072, 2048);
  transpose_cast<<<dim3(32, 48), 256, 0, stream>>>(vw, vw_t, 3072, 2048);
  transpose_cast<<<dim3(48, 64), 256, 0, stream>>>(ow, ow_t, 4096, 3072);

  gemm_bf16<false><<<dim3(32, 32), 256, 0, stream>>>(x_bf, qw_t, xq, 4096, 4096, 3072);
  gemm_bf16<false><<<dim3(16, 32), 256, 0, stream>>>(x_bf, kw_t, xk, 4096, 2048, 3072);
  gemm_bf16<false><<<dim3(16, 32), 256, 0, stream>>>(x_bf, vw_t, xv, 4096, 2048, 3072);

  rmsnorm_rope<<<dim3(4096, 4), 256, 0, stream>>>(xq, qnw, fc, fsn, 16, SCALE_);
  rmsnorm_rope<<<dim3(4096, 2), 256, 0, stream>>>(xk, knw, fc, fsn, 8, 1.0f);

  flash_attn<<<dim3(32, 16, 2), 256, 0, stream>>>(xq, xk, xv, attn);

  gemm_bf16<true><<<dim3(24, 32), 256, 0, stream>>>(attn, ow_t, (float*)d_out, 4096, 3072, 4096);
}